// Round 2
// baseline (2236.074 us; speedup 1.0000x reference)
//
#include <hip/hip_runtime.h>
#include <hip/hip_bf16.h>

typedef unsigned int u32;

// order-preserving float->uint encoding for atomicMax on floats
// (identity element: 0 — every real float encodes > 0)
__device__ __forceinline__ u32 fenc(float f) {
  u32 u = __float_as_uint(f);
  return (u & 0x80000000u) ? ~u : (u | 0x80000000u);
}
__device__ __forceinline__ float fdec(u32 u) {
  u32 b = (u & 0x80000000u) ? (u & 0x7FFFFFFFu) : ~u;
  return __uint_as_float(b);
}

// C[M,N] = A[M,K] @ B[K,N] + bias[N], all f32. 64x64 tile, 256 thr, 4x4/thr.
__global__ __launch_bounds__(256) void gemm_bias_kernel(
    const float* __restrict__ A, const float* __restrict__ B,
    const float* __restrict__ bias, float* __restrict__ C, int M, int N, int K) {
  __shared__ float As[16][65];
  __shared__ float Bs[16][65];
  const int tid = threadIdx.x;
  const int brow = blockIdx.y * 64, bcol = blockIdx.x * 64;
  const int tr = tid >> 4, tc = tid & 15;
  float acc[4][4] = {};
  for (int k0 = 0; k0 < K; k0 += 16) {
#pragma unroll
    for (int i = 0; i < 4; ++i) {
      int idx = tid + i * 256;
      int r = idx >> 4, c = idx & 15;
      int gr = brow + r;
      As[c][r] = (gr < M) ? A[(size_t)gr * K + k0 + c] : 0.f;
    }
#pragma unroll
    for (int i = 0; i < 4; ++i) {
      int idx = tid + i * 256;
      int r = idx >> 6, c = idx & 63;
      Bs[r][c] = B[(size_t)(k0 + r) * N + bcol + c];
    }
    __syncthreads();
#pragma unroll
    for (int kk = 0; kk < 16; ++kk) {
      float a[4], b[4];
#pragma unroll
      for (int i = 0; i < 4; ++i) a[i] = As[kk][tr * 4 + i];
#pragma unroll
      for (int j = 0; j < 4; ++j) b[j] = Bs[kk][tc * 4 + j];
#pragma unroll
      for (int i = 0; i < 4; ++i)
#pragma unroll
        for (int j = 0; j < 4; ++j) acc[i][j] += a[i] * b[j];
    }
    __syncthreads();
  }
#pragma unroll
  for (int i = 0; i < 4; ++i) {
    int gr = brow + tr * 4 + i;
    if (gr >= M) continue;
#pragma unroll
    for (int j = 0; j < 4; ++j) {
      int gc = bcol + tc * 4 + j;
      C[(size_t)gr * N + gc] = acc[i][j] + bias[gc];
    }
  }
}

// one wave per edge: logits[e,h] = sum_c leaky(xl[src]+xr[dst]+ee)*att ; atomicMax lmax
template <int HC, int C>
__global__ __launch_bounds__(256) void edge_logits_kernel(
    const float* __restrict__ xl, const float* __restrict__ xr,
    const float* __restrict__ ea, const float* __restrict__ We,
    const float* __restrict__ att, const int* __restrict__ src,
    const int* __restrict__ dst, float* __restrict__ logits,
    u32* __restrict__ lmax, int E) {
  const int e = (blockIdx.x * 256 + threadIdx.x) >> 6;
  const int lane = threadIdx.x & 63;
  if (e >= E) return;
  const int s = src[e], d = dst[e];
  const float ea0 = ea[3 * e], ea1 = ea[3 * e + 1], ea2 = ea[3 * e + 2];
  const float* xls = xl + (size_t)s * HC;
  const float* xrd = xr + (size_t)d * HC;
  float hs[4] = {0.f, 0.f, 0.f, 0.f};
#pragma unroll
  for (int t = 0; t < HC / 64; ++t) {
    const int j = t * 64 + lane;
    float w = ea0 * We[j] + ea1 * We[HC + j] + ea2 * We[2 * HC + j];
    float v = xls[j] + xrd[j] + w;
    v = (v > 0.f) ? v : 0.2f * v;
    hs[t / (C / 64)] += v * att[j];
  }
#pragma unroll
  for (int off = 32; off; off >>= 1) {
#pragma unroll
    for (int h = 0; h < 4; ++h) hs[h] += __shfl_xor(hs[h], off);
  }
  if (lane < 4) {
    logits[(size_t)e * 4 + lane] = hs[lane];
    atomicMax(&lmax[d * 4 + lane], fenc(hs[lane]));
  }
}

// logits -> ex (in place), denom += ex
__global__ __launch_bounds__(256) void edge_ex_kernel(
    float* __restrict__ lx, const u32* __restrict__ lmax,
    float* __restrict__ denom, const int* __restrict__ dst, int E) {
  const int i = blockIdx.x * 256 + threadIdx.x;
  if (i >= E * 4) return;
  const int h = i & 3, e = i >> 2;
  const int d = dst[e];
  const float ex = expf(lx[i] - fdec(lmax[d * 4 + h]));
  lx[i] = ex;
  atomicAdd(&denom[d * 4 + h], ex);
}

// one wave per edge: out[dst] += alpha * xl[src]; optionally emit alpha
template <int HC, int C, bool WA>
__global__ __launch_bounds__(256) void edge_aggr_kernel(
    const float* __restrict__ xl, const float* __restrict__ ex,
    const float* __restrict__ denom, const int* __restrict__ src,
    const int* __restrict__ dst, float* __restrict__ out,
    float* __restrict__ alpha_out, int E) {
  const int e = (blockIdx.x * 256 + threadIdx.x) >> 6;
  const int lane = threadIdx.x & 63;
  if (e >= E) return;
  const int s = src[e], d = dst[e];
  float alf[4];
#pragma unroll
  for (int h = 0; h < 4; ++h) alf[h] = ex[(size_t)e * 4 + h] / denom[d * 4 + h];
  if (WA && lane < 4) alpha_out[(size_t)e * 4 + lane] = alf[lane];
  const float* xls = xl + (size_t)s * HC;
  float* od = out + (size_t)d * HC;
#pragma unroll
  for (int t = 0; t < HC / 64; ++t) {
    const int j = t * 64 + lane;
    atomicAdd(&od[j], alf[t / (C / 64)] * xls[j]);
  }
}

// out = (SILU ? silu(in+bias) : in+bias) ; NC power of two
template <bool SILU>
__global__ __launch_bounds__(256) void bias_act_kernel(
    const float* __restrict__ in, const float* __restrict__ bias,
    float* __restrict__ out, int n, int NC) {
  const int i = blockIdx.x * 256 + threadIdx.x;
  if (i >= n) return;
  float v = in[i] + bias[i & (NC - 1)];
  if (SILU) v = v / (1.f + expf(-v));
  out[i] = v;
}

extern "C" void kernel_launch(void* const* d_in, const int* in_sizes, int n_in,
                              void* d_out, int out_size, void* d_ws, size_t ws_size,
                              hipStream_t stream) {
  const float* x    = (const float*)d_in[0];
  const int*   ei   = (const int*)d_in[1];
  const float* ea   = (const float*)d_in[2];
  const float* W1l  = (const float*)d_in[3];
  const float* b1l  = (const float*)d_in[4];
  const float* W1r  = (const float*)d_in[5];
  const float* b1r  = (const float*)d_in[6];
  const float* W1e  = (const float*)d_in[7];
  const float* att1 = (const float*)d_in[8];
  const float* bias1= (const float*)d_in[9];
  const float* W2l  = (const float*)d_in[10];
  const float* b2l  = (const float*)d_in[11];
  const float* W2r  = (const float*)d_in[12];
  const float* b2r  = (const float*)d_in[13];
  const float* W2e  = (const float*)d_in[14];
  const float* att2 = (const float*)d_in[15];
  const float* bias2= (const float*)d_in[16];
  const float* Wp   = (const float*)d_in[17];
  const float* bp   = (const float*)d_in[18];

  const int N = in_sizes[0] / 256;  // 10000
  const int E = in_sizes[1] / 2;    // 320000
  const int* srcI = ei;
  const int* dstI = ei + E;

  // workspace layout (f32 units), ~92.5 MB total:
  //   A  : N*1024               xl (layer2 size; layer1 uses first N*256)
  //   Bf : N*1024               xr, then aggregation accumulator
  //   X  : max(N*256, E*4)      hbuf (h after silu)  ALIASED WITH  logits/ex
  //        (logits1 dead before hbuf written; hbuf dead before logits2 written)
  //   lmax : N*4 u32 ; denom : N*4 f32
  float* wsf = (float*)d_ws;
  float* A    = wsf;
  float* Bf   = wsf + (size_t)N * 1024;
  float* X    = wsf + (size_t)N * 2048;
  const size_t xelems = ((size_t)N * 256 > (size_t)E * 4) ? (size_t)N * 256 : (size_t)E * 4;
  u32*   lmax  = (u32*)(X + xelems);
  float* denom = (float*)(lmax + (size_t)N * 4);
  float* hbuf   = X;
  float* logits = X;

  float* yout = (float*)d_out;
  float* alpha_out = yout + (size_t)N * 256;

  const dim3 gN256(256 / 64, (N + 63) / 64);
  const dim3 gN1024(1024 / 64, (N + 63) / 64);
  const int eBlocks = (E + 3) / 4;
  const int ehBlocks = (E * 4 + 255) / 256;

  // ---------------- layer 1 (H=4, C=64, HC=256) ----------------
  gemm_bias_kernel<<<gN256, 256, 0, stream>>>(x, W1l, b1l, A, N, 256, 256);
  gemm_bias_kernel<<<gN256, 256, 0, stream>>>(x, W1r, b1r, Bf, N, 256, 256);
  hipMemsetAsync(lmax, 0, (size_t)N * 4 * 4 * 2, stream);  // lmax + denom (adjacent)
  edge_logits_kernel<256, 64><<<eBlocks, 256, 0, stream>>>(A, Bf, ea, W1e, att1,
                                                           srcI, dstI, logits, lmax, E);
  edge_ex_kernel<<<ehBlocks, 256, 0, stream>>>(logits, lmax, denom, dstI, E);
  hipMemsetAsync(Bf, 0, (size_t)N * 256 * 4, stream);
  edge_aggr_kernel<256, 64, false><<<eBlocks, 256, 0, stream>>>(A, logits, denom,
                                                                srcI, dstI, Bf, nullptr, E);
  bias_act_kernel<true><<<((size_t)N * 256 + 255) / 256, 256, 0, stream>>>(Bf, bias1, hbuf,
                                                                           N * 256, 256);

  // ---------------- layer 2 (H=4, C=256, HC=1024) ----------------
  gemm_bias_kernel<<<gN1024, 256, 0, stream>>>(hbuf, W2l, b2l, A, N, 1024, 256);
  gemm_bias_kernel<<<gN1024, 256, 0, stream>>>(hbuf, W2r, b2r, Bf, N, 1024, 256);
  hipMemsetAsync(lmax, 0, (size_t)N * 4 * 4 * 2, stream);
  edge_logits_kernel<1024, 256><<<eBlocks, 256, 0, stream>>>(A, Bf, ea, W2e, att2,
                                                             srcI, dstI, logits, lmax, E);
  edge_ex_kernel<<<ehBlocks, 256, 0, stream>>>(logits, lmax, denom, dstI, E);
  // NOTE: from here on, layer-2 aggregation accumulates into Bf (xr2 dead after logits)
  hipMemsetAsync(Bf, 0, (size_t)N * 1024 * 4, stream);
  edge_aggr_kernel<1024, 256, true><<<eBlocks, 256, 0, stream>>>(A, logits, denom,
                                                                 srcI, dstI, Bf, alpha_out, E);
  // out2 = Bf + bias2 -> write into A (A/xl2 dead after edge_aggr)
  bias_act_kernel<false><<<((size_t)N * 1024 + 255) / 256, 256, 0, stream>>>(Bf, bias2, A,
                                                                             N * 1024, 1024);
  gemm_bias_kernel<<<gN256, 256, 0, stream>>>(A, Wp, bp, yout, N, 256, 1024);
}

// Round 3
// 883.707 us; speedup vs baseline: 2.5303x; 2.5303x over previous
//
#include <hip/hip_runtime.h>
#include <hip/hip_bf16.h>

// ---------------- GEMM: C[M,N] = A[M,K] @ B[K,N] + bias[N], f32 ----------------
__global__ __launch_bounds__(256) void gemm_bias_kernel(
    const float* __restrict__ A, const float* __restrict__ B,
    const float* __restrict__ bias, float* __restrict__ C, int M, int N, int K) {
  __shared__ float As[16][65];
  __shared__ float Bs[16][65];
  const int tid = threadIdx.x;
  const int brow = blockIdx.y * 64, bcol = blockIdx.x * 64;
  const int tr = tid >> 4, tc = tid & 15;
  float acc[4][4] = {};
  for (int k0 = 0; k0 < K; k0 += 16) {
#pragma unroll
    for (int i = 0; i < 4; ++i) {
      int idx = tid + i * 256;
      int r = idx >> 4, c = idx & 15;
      int gr = brow + r;
      As[c][r] = (gr < M) ? A[(size_t)gr * K + k0 + c] : 0.f;
    }
#pragma unroll
    for (int i = 0; i < 4; ++i) {
      int idx = tid + i * 256;
      int r = idx >> 6, c = idx & 63;
      Bs[r][c] = B[(size_t)(k0 + r) * N + bcol + c];
    }
    __syncthreads();
#pragma unroll
    for (int kk = 0; kk < 16; ++kk) {
      float a[4], b[4];
#pragma unroll
      for (int i = 0; i < 4; ++i) a[i] = As[kk][tr * 4 + i];
#pragma unroll
      for (int j = 0; j < 4; ++j) b[j] = Bs[kk][tc * 4 + j];
#pragma unroll
      for (int i = 0; i < 4; ++i)
#pragma unroll
        for (int j = 0; j < 4; ++j) acc[i][j] += a[i] * b[j];
    }
    __syncthreads();
  }
#pragma unroll
  for (int i = 0; i < 4; ++i) {
    int gr = brow + tr * 4 + i;
    if (gr >= M) continue;
#pragma unroll
    for (int j = 0; j < 4; ++j) {
      int gc = bcol + tc * 4 + j;
      C[(size_t)gr * N + gc] = acc[i][j] + bias[gc];
    }
  }
}

// ---------------- CSR build ----------------
__global__ __launch_bounds__(256) void hist_kernel(const int* __restrict__ dst,
                                                   int* __restrict__ P, int E) {
  int i = blockIdx.x * 256 + threadIdx.x;
  if (i < E) atomicAdd(&P[dst[i]], 1);
}

// in-place exclusive scan of P[0..n), single block of 256 threads
__global__ __launch_bounds__(256) void scan_kernel(int* __restrict__ P, int n) {
  __shared__ int buf[256];
  __shared__ int carry;
  if (threadIdx.x == 0) carry = 0;
  __syncthreads();
  for (int base = 0; base < n; base += 256) {
    int i = base + threadIdx.x;
    int v = (i < n) ? P[i] : 0;
    buf[threadIdx.x] = v;
    __syncthreads();
#pragma unroll
    for (int off = 1; off < 256; off <<= 1) {
      int t = (threadIdx.x >= off) ? buf[threadIdx.x - off] : 0;
      __syncthreads();
      buf[threadIdx.x] += t;
      __syncthreads();
    }
    int excl = buf[threadIdx.x] - v + carry;
    if (i < n) P[i] = excl;
    int tot = buf[255];
    __syncthreads();
    if (threadIdx.x == 0) carry += tot;
    __syncthreads();
  }
}

// scatter edge ids into buckets; afterwards P[d] = end offset of bucket d
__global__ __launch_bounds__(256) void scatter_kernel(const int* __restrict__ dst,
                                                      int* __restrict__ P,
                                                      int* __restrict__ perm, int E) {
  int i = blockIdx.x * 256 + threadIdx.x;
  if (i < E) {
    int pos = atomicAdd(&P[dst[i]], 1);
    perm[pos] = i;
  }
}

// ---------------- fused GATv2 edge phase: one block per destination node ----------
// 256 threads = 4 waves; wave w owns head w (64 lanes x CPT channels = C per head).
// CPT channels per thread; HC = 256*CPT.
template <int CPT, bool SILU, bool WLOG>
__global__ __launch_bounds__(256) void fused_gat_kernel(
    const float* __restrict__ xl, const float* __restrict__ xr,
    const float* __restrict__ ea, const float* __restrict__ We,
    const float* __restrict__ att, const int* __restrict__ src,
    const int* __restrict__ Pend, const int* __restrict__ perm,
    const float* __restrict__ bias, float* __restrict__ out,
    float* __restrict__ logit_out, float* __restrict__ mfin,
    float* __restrict__ sfin) {
  constexpr int HC = 256 * CPT;
  const int d = blockIdx.x;
  const int tid = threadIdx.x;
  const int lane = tid & 63;
  const int w = tid >> 6;
  const int beg = (d == 0) ? 0 : Pend[d - 1];
  const int end = Pend[d];

  float xrv[CPT], attv[CPT], we0[CPT], we1[CPT], we2[CPT];
#pragma unroll
  for (int c = 0; c < CPT; ++c) {
    int j = tid * CPT + c;
    xrv[c] = xr[(size_t)d * HC + j];
    attv[c] = att[j];
    we0[c] = We[j];
    we1[c] = We[HC + j];
    we2[c] = We[2 * HC + j];
  }

  float m_run = -INFINITY, ssum = 0.f, acc[CPT];
#pragma unroll
  for (int c = 0; c < CPT; ++c) acc[c] = 0.f;

  __shared__ int s_eid[64];
  __shared__ int s_src[64];
  __shared__ float s_ea0[64], s_ea1[64], s_ea2[64];

  for (int base = beg; base < end; base += 64) {
    const int nb = min(64, end - base);
    if (tid < nb) {
      int eid = perm[base + tid];
      s_eid[tid] = eid;
      s_src[tid] = src[eid];
      s_ea0[tid] = ea[(size_t)eid * 3];
      s_ea1[tid] = ea[(size_t)eid * 3 + 1];
      s_ea2[tid] = ea[(size_t)eid * 3 + 2];
    }
    __syncthreads();

    // software-pipelined gather of xl rows
    float xln[CPT];
    {
      const float* p0 = xl + (size_t)s_src[0] * HC + tid * CPT;
      if (CPT == 4) {
        float4 v = *(const float4*)p0;
        xln[0] = v.x; xln[1] = v.y; xln[2] = v.z; xln[3] = v.w;
      } else {
        xln[0] = p0[0];
      }
    }
    for (int i = 0; i < nb; ++i) {
      float xlv[CPT];
#pragma unroll
      for (int c = 0; c < CPT; ++c) xlv[c] = xln[c];
      if (i + 1 < nb) {
        const float* pn = xl + (size_t)s_src[i + 1] * HC + tid * CPT;
        if (CPT == 4) {
          float4 v = *(const float4*)pn;
          xln[0] = v.x; xln[1] = v.y; xln[2] = v.z; xln[3] = v.w;
        } else {
          xln[0] = pn[0];
        }
      }
      const float e0 = s_ea0[i], e1 = s_ea1[i], e2 = s_ea2[i];
      float p = 0.f;
#pragma unroll
      for (int c = 0; c < CPT; ++c) {
        float v = xlv[c] + xrv[c] + e0 * we0[c] + e1 * we1[c] + e2 * we2[c];
        v = (v > 0.f) ? v : 0.2f * v;
        p += v * attv[c];
      }
#pragma unroll
      for (int off = 32; off; off >>= 1) p += __shfl_xor(p, off);

      const float nm = fmaxf(m_run, p);
      const float scale = expf(m_run - nm);
      const float pe = expf(p - nm);
      ssum = ssum * scale + pe;
#pragma unroll
      for (int c = 0; c < CPT; ++c) acc[c] = acc[c] * scale + pe * xlv[c];
      m_run = nm;
      if (WLOG && lane == 0) logit_out[(size_t)s_eid[i] * 4 + w] = p;
    }
    __syncthreads();
  }

  const float inv = (end > beg) ? 1.f / ssum : 0.f;
#pragma unroll
  for (int c = 0; c < CPT; ++c) {
    int j = tid * CPT + c;
    float o = acc[c] * inv + bias[j];
    if (SILU) o = o / (1.f + expf(-o));
    out[(size_t)d * HC + j] = o;
  }
  if (WLOG && lane == 0) {
    mfin[d * 4 + w] = m_run;
    sfin[d * 4 + w] = ssum;
  }
}

// in-place: logit -> alpha = exp(l - mfin[dst])/sfin[dst]
__global__ __launch_bounds__(256) void alpha_kernel(
    float* __restrict__ la, const float* __restrict__ mfin,
    const float* __restrict__ sfin, const int* __restrict__ dst, int n4) {
  int i = blockIdx.x * 256 + threadIdx.x;
  if (i >= n4) return;
  int e = i >> 2, h = i & 3;
  int d = dst[e];
  la[i] = expf(la[i] - mfin[d * 4 + h]) / sfin[d * 4 + h];
}

extern "C" void kernel_launch(void* const* d_in, const int* in_sizes, int n_in,
                              void* d_out, int out_size, void* d_ws, size_t ws_size,
                              hipStream_t stream) {
  const float* x    = (const float*)d_in[0];
  const int*   ei   = (const int*)d_in[1];
  const float* ea   = (const float*)d_in[2];
  const float* W1l  = (const float*)d_in[3];
  const float* b1l  = (const float*)d_in[4];
  const float* W1r  = (const float*)d_in[5];
  const float* b1r  = (const float*)d_in[6];
  const float* W1e  = (const float*)d_in[7];
  const float* att1 = (const float*)d_in[8];
  const float* bias1= (const float*)d_in[9];
  const float* W2l  = (const float*)d_in[10];
  const float* b2l  = (const float*)d_in[11];
  const float* W2r  = (const float*)d_in[12];
  const float* b2r  = (const float*)d_in[13];
  const float* W2e  = (const float*)d_in[14];
  const float* att2 = (const float*)d_in[15];
  const float* bias2= (const float*)d_in[16];
  const float* Wp   = (const float*)d_in[17];
  const float* bp   = (const float*)d_in[18];

  const int N = in_sizes[0] / 256;  // 10000
  const int E = in_sizes[1] / 2;    // 320000
  const int* srcI = ei;
  const int* dstI = ei + E;

  // workspace (~83.6 MB):
  float* wsf = (float*)d_ws;
  float* A    = wsf;                        // N*1024 : xl
  float* Bf   = A + (size_t)N * 1024;       // N*1024 : xr, then out2 (row-exclusive in-place)
  int*   P    = (int*)(Bf + (size_t)N * 1024);  // N : counts->offsets->ends
  int*   perm = P + N;                      // E : edge ids sorted by dst
  float* mfin = (float*)(perm + E);         // N*4
  float* sfin = mfin + (size_t)N * 4;       // N*4

  float* yout = (float*)d_out;              // N*256 ; doubles as h-scratch between layers
  float* alpha_out = yout + (size_t)N * 256;  // E*4 ; doubles as logit scratch

  const dim3 gN256(256 / 64, (N + 63) / 64);
  const dim3 gN1024(1024 / 64, (N + 63) / 64);
  const int eB = (E + 255) / 256;

  // CSR build (shared by both layers)
  hipMemsetAsync(P, 0, (size_t)N * 4, stream);
  hist_kernel<<<eB, 256, 0, stream>>>(dstI, P, E);
  scan_kernel<<<1, 256, 0, stream>>>(P, N);
  scatter_kernel<<<eB, 256, 0, stream>>>(dstI, P, perm, E);

  // ---------------- layer 1 (HC=256, CPT=1) ----------------
  gemm_bias_kernel<<<gN256, 256, 0, stream>>>(x, W1l, b1l, A, N, 256, 256);
  gemm_bias_kernel<<<gN256, 256, 0, stream>>>(x, W1r, b1r, Bf, N, 256, 256);
  fused_gat_kernel<1, true, false><<<N, 256, 0, stream>>>(
      A, Bf, ea, W1e, att1, srcI, P, perm, bias1, yout /*h*/, nullptr, nullptr, nullptr);

  // ---------------- layer 2 (HC=1024, CPT=4) ----------------
  gemm_bias_kernel<<<gN1024, 256, 0, stream>>>(yout, W2l, b2l, A, N, 1024, 256);
  gemm_bias_kernel<<<gN1024, 256, 0, stream>>>(yout, W2r, b2r, Bf, N, 1024, 256);
  fused_gat_kernel<4, false, true><<<N, 256, 0, stream>>>(
      A, Bf, ea, W2e, att2, srcI, P, perm, bias2, Bf /*out2 in-place*/, alpha_out,
      mfin, sfin);
  alpha_kernel<<<(E * 4 + 255) / 256, 256, 0, stream>>>(alpha_out, mfin, sfin, dstI, E * 4);

  // projector
  gemm_bias_kernel<<<gN256, 256, 0, stream>>>(Bf, Wp, bp, yout, N, 256, 1024);
}

// Round 4
// 555.984 us; speedup vs baseline: 4.0218x; 1.5894x over previous
//
#include <hip/hip_runtime.h>
#include <hip/hip_bf16.h>

typedef __hip_bfloat16 hbf16;
typedef __attribute__((ext_vector_type(8))) short bf16x8;
typedef __attribute__((ext_vector_type(4))) float f32x4;

__device__ __forceinline__ void storeO(float* p, float v) { *p = v; }
__device__ __forceinline__ void storeO(hbf16* p, float v) { *p = __float2bfloat16(v); }

// ---------------- f32 -> bf16 convert (4 elems/thread) ----------------
__global__ __launch_bounds__(256) void cvt_kernel(const float* __restrict__ in,
                                                  hbf16* __restrict__ out, int n) {
  int i = (blockIdx.x * 256 + threadIdx.x) * 4;
  if (i >= n) return;
  float4 v = *(const float4*)(in + i);
  out[i] = __float2bfloat16(v.x);
  out[i + 1] = __float2bfloat16(v.y);
  out[i + 2] = __float2bfloat16(v.z);
  out[i + 3] = __float2bfloat16(v.w);
}

// ---------------- W[K][N] f32 -> Wt[N][K] bf16 (32x32 tiles) ----------------
__global__ __launch_bounds__(256) void transpose_cvt_kernel(
    const float* __restrict__ W, hbf16* __restrict__ Wt, int K, int N) {
  __shared__ hbf16 tile[32][33];
  const int n0 = blockIdx.x * 32, k0 = blockIdx.y * 32;
  const int tx = threadIdx.x, ty = threadIdx.y;  // 32 x 8
#pragma unroll
  for (int i = 0; i < 4; ++i)
    tile[ty * 4 + i][tx] = __float2bfloat16(W[(size_t)(k0 + ty * 4 + i) * N + n0 + tx]);
  __syncthreads();
#pragma unroll
  for (int i = 0; i < 4; ++i)
    Wt[(size_t)(n0 + ty * 4 + i) * K + k0 + tx] = tile[tx][ty * 4 + i];
}

// ---------------- MFMA GEMM: C[M,N](f32) = A[M,K](bf16) @ Bt[N,K](bf16)^T + bias ----
// 128x128 tile, 256 thr = 2x2 waves, each wave 64x64 = 4x4 mfma_16x16x32 frags.
__global__ __launch_bounds__(256) void mfma_gemm_kernel(
    const hbf16* __restrict__ A, const hbf16* __restrict__ Bt,
    const float* __restrict__ bias, float* __restrict__ C, int M, int N, int K) {
  const int tid = threadIdx.x, lane = tid & 63, w = tid >> 6;
  const int wr = w >> 1, wc = w & 1;
  const int rowb = blockIdx.y * 128 + wr * 64;
  const int colb = blockIdx.x * 128 + wc * 64;
  const int lr = lane & 15, lk = (lane >> 4) * 8;

  f32x4 acc[4][4];
#pragma unroll
  for (int mi = 0; mi < 4; ++mi)
#pragma unroll
    for (int ni = 0; ni < 4; ++ni) acc[mi][ni] = {0.f, 0.f, 0.f, 0.f};

  const short* Ap = (const short*)A;
  const short* Bp = (const short*)Bt;

  int ar[4];
#pragma unroll
  for (int mi = 0; mi < 4; ++mi) {
    int r = rowb + mi * 16 + lr;
    ar[mi] = (r < M) ? r : (M - 1);  // clamp: garbage rows never stored
  }

#pragma unroll 2
  for (int k0 = 0; k0 < K; k0 += 32) {
    bf16x8 af[4], bfr[4];
#pragma unroll
    for (int mi = 0; mi < 4; ++mi)
      af[mi] = *(const bf16x8*)(Ap + (size_t)ar[mi] * K + k0 + lk);
#pragma unroll
    for (int ni = 0; ni < 4; ++ni)
      bfr[ni] = *(const bf16x8*)(Bp + (size_t)(colb + ni * 16 + lr) * K + k0 + lk);
#pragma unroll
    for (int mi = 0; mi < 4; ++mi)
#pragma unroll
      for (int ni = 0; ni < 4; ++ni)
        acc[mi][ni] = __builtin_amdgcn_mfma_f32_16x16x32_bf16(af[mi], bfr[ni],
                                                              acc[mi][ni], 0, 0, 0);
  }

  float bv[4];
#pragma unroll
  for (int ni = 0; ni < 4; ++ni) bv[ni] = bias[colb + ni * 16 + lr];
#pragma unroll
  for (int mi = 0; mi < 4; ++mi) {
    const int row0 = rowb + mi * 16 + (lane >> 4) * 4;
#pragma unroll
    for (int r = 0; r < 4; ++r) {
      const int row = row0 + r;
      if (row >= M) continue;
#pragma unroll
      for (int ni = 0; ni < 4; ++ni)
        C[(size_t)row * N + colb + ni * 16 + lr] = acc[mi][ni][r] + bv[ni];
    }
  }
}

// ---------------- CSR build ----------------
__global__ __launch_bounds__(256) void hist_kernel(const int* __restrict__ dst,
                                                   int* __restrict__ P, int E) {
  int i = blockIdx.x * 256 + threadIdx.x;
  if (i < E) atomicAdd(&P[dst[i]], 1);
}

__global__ __launch_bounds__(256) void scan_kernel(int* __restrict__ P, int n) {
  __shared__ int buf[256];
  __shared__ int carry;
  if (threadIdx.x == 0) carry = 0;
  __syncthreads();
  for (int base = 0; base < n; base += 256) {
    int i = base + threadIdx.x;
    int v = (i < n) ? P[i] : 0;
    buf[threadIdx.x] = v;
    __syncthreads();
#pragma unroll
    for (int off = 1; off < 256; off <<= 1) {
      int t = (threadIdx.x >= off) ? buf[threadIdx.x - off] : 0;
      __syncthreads();
      buf[threadIdx.x] += t;
      __syncthreads();
    }
    int excl = buf[threadIdx.x] - v + carry;
    if (i < n) P[i] = excl;
    int tot = buf[255];
    __syncthreads();
    if (threadIdx.x == 0) carry += tot;
    __syncthreads();
  }
}

__global__ __launch_bounds__(256) void scatter_kernel(const int* __restrict__ dst,
                                                      int* __restrict__ P,
                                                      int* __restrict__ perm, int E) {
  int i = blockIdx.x * 256 + threadIdx.x;
  if (i < E) {
    int pos = atomicAdd(&P[dst[i]], 1);
    perm[pos] = i;
  }
}

// ---------------- fused GATv2 edge phase: one block per destination node ----------
template <int CPT, bool SILU, bool WLOG, typename OutT>
__global__ __launch_bounds__(256) void fused_gat_kernel(
    const float* __restrict__ xl, const float* __restrict__ xr,
    const float* __restrict__ ea, const float* __restrict__ We,
    const float* __restrict__ att, const int* __restrict__ src,
    const int* __restrict__ Pend, const int* __restrict__ perm,
    const float* __restrict__ bias, OutT* __restrict__ out,
    float* __restrict__ logit_out, float* __restrict__ mfin,
    float* __restrict__ sfin) {
  constexpr int HC = 256 * CPT;
  const int d = blockIdx.x;
  const int tid = threadIdx.x;
  const int lane = tid & 63;
  const int w = tid >> 6;
  const int beg = (d == 0) ? 0 : Pend[d - 1];
  const int end = Pend[d];

  float xrv[CPT], attv[CPT], we0[CPT], we1[CPT], we2[CPT];
#pragma unroll
  for (int c = 0; c < CPT; ++c) {
    int j = tid * CPT + c;
    xrv[c] = xr[(size_t)d * HC + j];
    attv[c] = att[j];
    we0[c] = We[j];
    we1[c] = We[HC + j];
    we2[c] = We[2 * HC + j];
  }

  float m_run = -INFINITY, ssum = 0.f, acc[CPT];
#pragma unroll
  for (int c = 0; c < CPT; ++c) acc[c] = 0.f;

  __shared__ int s_eid[64];
  __shared__ int s_src[64];
  __shared__ float s_ea0[64], s_ea1[64], s_ea2[64];

  for (int base = beg; base < end; base += 64) {
    const int nb = min(64, end - base);
    if (tid < nb) {
      int eid = perm[base + tid];
      s_eid[tid] = eid;
      s_src[tid] = src[eid];
      s_ea0[tid] = ea[(size_t)eid * 3];
      s_ea1[tid] = ea[(size_t)eid * 3 + 1];
      s_ea2[tid] = ea[(size_t)eid * 3 + 2];
    }
    __syncthreads();

    float xln[CPT];
    {
      const float* p0 = xl + (size_t)s_src[0] * HC + tid * CPT;
      if (CPT == 4) {
        float4 v = *(const float4*)p0;
        xln[0] = v.x; xln[1] = v.y; xln[2] = v.z; xln[3] = v.w;
      } else {
        xln[0] = p0[0];
      }
    }
    for (int i = 0; i < nb; ++i) {
      float xlv[CPT];
#pragma unroll
      for (int c = 0; c < CPT; ++c) xlv[c] = xln[c];
      if (i + 1 < nb) {
        const float* pn = xl + (size_t)s_src[i + 1] * HC + tid * CPT;
        if (CPT == 4) {
          float4 v = *(const float4*)pn;
          xln[0] = v.x; xln[1] = v.y; xln[2] = v.z; xln[3] = v.w;
        } else {
          xln[0] = pn[0];
        }
      }
      const float e0 = s_ea0[i], e1 = s_ea1[i], e2 = s_ea2[i];
      float p = 0.f;
#pragma unroll
      for (int c = 0; c < CPT; ++c) {
        float v = xlv[c] + xrv[c] + e0 * we0[c] + e1 * we1[c] + e2 * we2[c];
        v = (v > 0.f) ? v : 0.2f * v;
        p += v * attv[c];
      }
#pragma unroll
      for (int off = 32; off; off >>= 1) p += __shfl_xor(p, off);

      // exact defer-rescale: p and m_run are wave-uniform -> uniform branch,
      // taken ~ln(deg) times per node instead of every edge
      if (p > m_run) {
        const float scale = expf(m_run - p);  // expf(-inf)=0 handles first edge
        ssum *= scale;
#pragma unroll
        for (int c = 0; c < CPT; ++c) acc[c] *= scale;
        m_run = p;
      }
      const float pe = expf(p - m_run);
      ssum += pe;
#pragma unroll
      for (int c = 0; c < CPT; ++c) acc[c] += pe * xlv[c];
      if (WLOG && lane == 0) logit_out[(size_t)s_eid[i] * 4 + w] = p;
    }
    __syncthreads();
  }

  const float inv = (end > beg) ? 1.f / ssum : 0.f;
#pragma unroll
  for (int c = 0; c < CPT; ++c) {
    int j = tid * CPT + c;
    float o = acc[c] * inv + bias[j];
    if (SILU) o = o / (1.f + expf(-o));
    storeO(&out[(size_t)d * HC + j], o);
  }
  if (WLOG && lane == 0) {
    mfin[d * 4 + w] = m_run;
    sfin[d * 4 + w] = ssum;
  }
}

// in-place: logit -> alpha = exp(l - mfin[dst]) / sfin[dst]
__global__ __launch_bounds__(256) void alpha_kernel(
    float* __restrict__ la, const float* __restrict__ mfin,
    const float* __restrict__ sfin, const int* __restrict__ dst, int n4) {
  int i = blockIdx.x * 256 + threadIdx.x;
  if (i >= n4) return;
  int e = i >> 2, h = i & 3;
  int d = dst[e];
  la[i] = expf(la[i] - mfin[d * 4 + h]) / sfin[d * 4 + h];
}

extern "C" void kernel_launch(void* const* d_in, const int* in_sizes, int n_in,
                              void* d_out, int out_size, void* d_ws, size_t ws_size,
                              hipStream_t stream) {
  const float* x    = (const float*)d_in[0];
  const int*   ei   = (const int*)d_in[1];
  const float* ea   = (const float*)d_in[2];
  const float* W1l  = (const float*)d_in[3];
  const float* b1l  = (const float*)d_in[4];
  const float* W1r  = (const float*)d_in[5];
  const float* b1r  = (const float*)d_in[6];
  const float* W1e  = (const float*)d_in[7];
  const float* att1 = (const float*)d_in[8];
  const float* bias1= (const float*)d_in[9];
  const float* W2l  = (const float*)d_in[10];
  const float* b2l  = (const float*)d_in[11];
  const float* W2r  = (const float*)d_in[12];
  const float* b2r  = (const float*)d_in[13];
  const float* W2e  = (const float*)d_in[14];
  const float* att2 = (const float*)d_in[15];
  const float* bias2= (const float*)d_in[16];
  const float* Wp   = (const float*)d_in[17];
  const float* bp   = (const float*)d_in[18];

  const int N = in_sizes[0] / 256;  // 10000
  const int E = in_sizes[1] / 2;    // 320000
  const int* srcI = ei;
  const int* dstI = ei + E;

  // workspace (~90.5 MB)
  float* wsf = (float*)d_ws;
  float* A    = wsf;                            // N*1024 f32: xl   (later: out2 bf16 alias)
  float* Bf   = A + (size_t)N * 1024;           // N*1024 f32: xr, then out2 f32 in-place
  int*   P    = (int*)(Bf + (size_t)N * 1024);  // N
  int*   perm = P + N;                          // E
  float* mfin = (float*)(perm + E);             // N*4
  float* sfin = mfin + (size_t)N * 4;           // N*4
  hbf16* xb   = (hbf16*)(sfin + (size_t)N * 4); // N*256 bf16 (x, then h)
  hbf16* W1lt = xb + (size_t)N * 256;           // 256*256
  hbf16* W1rt = W1lt + 256 * 256;
  hbf16* W2lt = W1rt + 256 * 256;               // 1024*256
  hbf16* W2rt = W2lt + 1024 * 256;
  hbf16* Wpt  = W2rt + 1024 * 256;              // 256*1024
  hbf16* out2b = (hbf16*)A;

  float* yout = (float*)d_out;                  // N*256
  float* alpha_out = yout + (size_t)N * 256;    // E*4

  const int eB = (E + 255) / 256;
  const dim3 tb(32, 8);

  // CSR build
  hipMemsetAsync(P, 0, (size_t)N * 4, stream);
  hist_kernel<<<eB, 256, 0, stream>>>(dstI, P, E);
  scan_kernel<<<1, 256, 0, stream>>>(P, N);
  scatter_kernel<<<eB, 256, 0, stream>>>(dstI, P, perm, E);

  // bf16 conversions
  cvt_kernel<<<(N * 256 / 4 + 255) / 256, 256, 0, stream>>>(x, xb, N * 256);
  transpose_cvt_kernel<<<dim3(256 / 32, 256 / 32), tb, 0, stream>>>(W1l, W1lt, 256, 256);
  transpose_cvt_kernel<<<dim3(256 / 32, 256 / 32), tb, 0, stream>>>(W1r, W1rt, 256, 256);
  transpose_cvt_kernel<<<dim3(1024 / 32, 256 / 32), tb, 0, stream>>>(W2l, W2lt, 256, 1024);
  transpose_cvt_kernel<<<dim3(1024 / 32, 256 / 32), tb, 0, stream>>>(W2r, W2rt, 256, 1024);
  transpose_cvt_kernel<<<dim3(256 / 32, 1024 / 32), tb, 0, stream>>>(Wp, Wpt, 1024, 256);

  const dim3 g256(256 / 128, (N + 127) / 128);
  const dim3 g1024(1024 / 128, (N + 127) / 128);

  // ---------------- layer 1 (HC=256, CPT=1) ----------------
  mfma_gemm_kernel<<<g256, 256, 0, stream>>>(xb, W1lt, b1l, A, N, 256, 256);
  mfma_gemm_kernel<<<g256, 256, 0, stream>>>(xb, W1rt, b1r, Bf, N, 256, 256);
  fused_gat_kernel<1, true, false, hbf16><<<N, 256, 0, stream>>>(
      A, Bf, ea, W1e, att1, srcI, P, perm, bias1, xb /*h, overwrites x-copy*/,
      nullptr, nullptr, nullptr);

  // ---------------- layer 2 (HC=1024, CPT=4) ----------------
  mfma_gemm_kernel<<<g1024, 256, 0, stream>>>(xb, W2lt, b2l, A, N, 1024, 256);
  mfma_gemm_kernel<<<g1024, 256, 0, stream>>>(xb, W2rt, b2r, Bf, N, 1024, 256);
  fused_gat_kernel<4, false, true, float><<<N, 256, 0, stream>>>(
      A, Bf, ea, W2e, att2, srcI, P, perm, bias2, Bf /*out2 in-place*/,
      alpha_out, mfin, sfin);
  alpha_kernel<<<(E * 4 + 255) / 256, 256, 0, stream>>>(alpha_out, mfin, sfin, dstI, E * 4);

  // projector: out2 f32 -> bf16 (into dead xl2 buffer), then MFMA GEMM
  cvt_kernel<<<((size_t)N * 1024 / 4 + 255) / 256, 256, 0, stream>>>(Bf, out2b, N * 1024);
  mfma_gemm_kernel<<<g256, 256, 0, stream>>>(out2b, Wpt, bp, yout, N, 256, 1024);
}